// Round 10
// baseline (140.780 us; speedup 1.0000x reference)
//
#include <hip/hip_runtime.h>

#define Hd 512
#define N2d 16
#define Rd 32
#define Ld 4096
#define NCHUNK 256
#define CLEN (Ld / NCHUNK)        // 16
#define NCH (Hd * N2d)            // 8192 chains
#define NGRP 16                   // chunks per prefix group
#define NGROUPS (NCHUNK / NGRP)   // 16

// ---------------------------------------------------------------------------
// Per-thread constant setup: 4 consecutive n of one h. fast == true when Are
// uniform and Aim arithmetic across the 4 (true for S4D init A = -1 + i*n).
// ---------------------------------------------------------------------------
__device__ __forceinline__ bool load_consts4(const float* A_log, const float* A_im,
        const float* B_param, int hnb,
        float* Are, float* Aim, float* BAr, float* BAi) {
    #pragma unroll
    for (int j = 0; j < 4; ++j) {
        int hn = hnb + j;
        Are[j] = -__expf(A_log[hn]);
        Aim[j] = A_im[hn];
        float Bre = B_param[2 * hn];
        float Bim = B_param[2 * hn + 1];
        float inv = __builtin_amdgcn_rcpf(Are[j] * Are[j] + Aim[j] * Aim[j]);
        BAr[j] = (Bre * Are[j] + Bim * Aim[j]) * inv;   // Bc*conj(A)/|A|^2
        BAi[j] = (Bim * Are[j] - Bre * Aim[j]) * inv;
    }
    float d1 = Aim[1] - Aim[0], d2 = Aim[2] - Aim[1], d3 = Aim[3] - Aim[2];
    return (Are[1] == Are[0]) && (Are[2] == Are[0]) && (Are[3] == Are[0]) &&
           (d1 == d2) && (d2 == d3);
}

// ---------------------------------------------------------------------------
// Kernel 1: dt = softplus(u@xprojT@dtwT + b); writes du[l][h] = (dt, u/dt).
// ---------------------------------------------------------------------------
__global__ __launch_bounds__(256) void k_dt(const float* __restrict__ u,
                                            const float* __restrict__ xproj_w,
                                            const float* __restrict__ dt_w,
                                            const float* __restrict__ dt_b,
                                            float2* __restrict__ du_out) {
    __shared__ float u_s[8][Hd];
    __shared__ float dtu_s[8][Rd];
    const int t = threadIdx.x;
    const int l0 = blockIdx.x * 8;

    #pragma unroll
    for (int i = 0; i < 16; ++i) {
        int idx = t + i * 256;
        ((float*)u_s)[idx] = u[l0 * Hd + idx];
    }
    __syncthreads();

    const int r = t >> 3;
    const int j = t & 7;
    float part[8];
    #pragma unroll
    for (int l = 0; l < 8; ++l) part[l] = 0.f;
    for (int k = 0; k < 64; ++k) {
        float w = xproj_w[r * Hd + k * 8 + j];
        #pragma unroll
        for (int l = 0; l < 8; ++l) part[l] = fmaf(u_s[l][k * 8 + j], w, part[l]);
    }
    #pragma unroll
    for (int off = 1; off < 8; off <<= 1) {
        #pragma unroll
        for (int l = 0; l < 8; ++l) part[l] += __shfl_xor(part[l], off);
    }
    if (j == 0) {
        #pragma unroll
        for (int l = 0; l < 8; ++l) dtu_s[l][r] = part[l];
    }
    __syncthreads();

    #pragma unroll
    for (int hb = 0; hb < 2; ++hb) {
        int h = hb * 256 + t;
        float bias = dt_b[h];
        float acc[8];
        #pragma unroll
        for (int l = 0; l < 8; ++l) acc[l] = bias;
        #pragma unroll
        for (int rb = 0; rb < 8; ++rb) {
            float4 w = *(const float4*)&dt_w[h * Rd + rb * 4];
            #pragma unroll
            for (int l = 0; l < 8; ++l) {
                acc[l] = fmaf(dtu_s[l][rb * 4 + 0], w.x, acc[l]);
                acc[l] = fmaf(dtu_s[l][rb * 4 + 1], w.y, acc[l]);
                acc[l] = fmaf(dtu_s[l][rb * 4 + 2], w.z, acc[l]);
                acc[l] = fmaf(dtu_s[l][rb * 4 + 3], w.w, acc[l]);
            }
        }
        #pragma unroll
        for (int l = 0; l < 8; ++l) {
            float x = acc[l];
            float sp = fmaxf(x, 0.f) + log1pf(__expf(-fabsf(x)));  // softplus
            float uv = u_s[l][h];
            float us = uv * __builtin_amdgcn_rcpf(fmaxf(sp, 1e-30f));
            du_out[(l0 + l) * Hd + h] = make_float2(sp, us);
        }
    }
}

// ---------------------------------------------------------------------------
// Kernel 2: per-chunk local scan (h0=0), CLEN=16. Emits:
//   Sb[c][chain] = S (chunk local state, float2)
//   Tc[c][h]     = chunk total dt (P = exp(A*Tc) is recomputed in k_comb)
//   y1T[l][h]    = (Re(C*S_local_l) + D*u_l, T_l)
// du staged in 4 pipelined batches of 4 (b0/b1 double buffer, static idx).
// Grid (256, 8) = 2048 blocks -> 8 blocks/CU; serial chain halved vs CLEN=32.
// ---------------------------------------------------------------------------
__global__ __launch_bounds__(256) void k_chunk(const float2* __restrict__ du,
        const float* __restrict__ A_log, const float* __restrict__ A_im,
        const float* __restrict__ B_param, const float* __restrict__ C_param,
        const float* __restrict__ Dp,
        float2* __restrict__ Sb, float* __restrict__ Tc,
        float2* __restrict__ y1T) {
    const int t = threadIdx.x;
    const int q = t & 3;
    const int hh = blockIdx.y * 64 + (t >> 2);
    const int c = blockIdx.x;
    const int hnb = hh * N2d + q * 4;
    const int lbase = c * CLEN;

    float Are[4], Aim[4], BAr[4], BAi[4], Cre[4], Cim[4];
    const bool fast = load_consts4(A_log, A_im, B_param, hnb, Are, Aim, BAr, BAi);
    #pragma unroll
    for (int jj = 0; jj < 4; ++jj) {
        Cre[jj] = C_param[2 * (hnb + jj)];
        Cim[jj] = C_param[2 * (hnb + jj) + 1];
    }
    const float Dv = Dp[hh];

    float sr[4] = {0.f, 0.f, 0.f, 0.f}, si[4] = {0.f, 0.f, 0.f, 0.f};
    float sdt = 0.f;

    float2 b0[4], b1[4];

    #define LOADB(buf, bb)                                                     \
        { _Pragma("unroll")                                                    \
          for (int k = 0; k < 4; ++k)                                          \
              buf[k] = du[(lbase + (bb) * 4 + k) * Hd + hh]; }

    if (fast) {
        const float Are0 = Are[0], Aim0 = Aim[0], dA = Aim[1] - Aim[0];
        #define STEPF(buf, bb)                                                 \
            { _Pragma("unroll")                                                \
              for (int k = 0; k < 4; ++k) {                                    \
                int l = lbase + (bb) * 4 + k;                                  \
                float dtv = buf[k].x, us = buf[k].y;                           \
                sdt += dtv;                                                    \
                float er = __expf(dtv * Are0);                                 \
                float s0, c0, sd, cd;                                          \
                __sincosf(dtv * Aim0, &s0, &c0);                               \
                __sincosf(dtv * dA, &sd, &cd);                                 \
                float ar = er * c0, ai = er * s0;                              \
                float yv = 0.f;                                                \
                _Pragma("unroll")                                              \
                for (int jj = 0; jj < 4; ++jj) {                               \
                    float gr = fmaf(ar, us, -us);                              \
                    float gi = ai * us;                                        \
                    float nr = fmaf(ar, sr[jj], fmaf(-ai, si[jj],              \
                                 fmaf(gr, BAr[jj], -gi * BAi[jj])));           \
                    float ni = fmaf(ar, si[jj], fmaf( ai, sr[jj],              \
                                 fmaf(gr, BAi[jj],  gi * BAr[jj])));           \
                    sr[jj] = nr; si[jj] = ni;                                  \
                    yv = fmaf(nr, Cre[jj], fmaf(-ni, Cim[jj], yv));            \
                    if (jj < 3) {                                              \
                        float tr = fmaf(ar, cd, -ai * sd);                     \
                        ai = fmaf(ai, cd, ar * sd);                            \
                        ar = tr;                                               \
                    }                                                          \
                }                                                              \
                yv += __shfl_xor(yv, 1);                                       \
                yv += __shfl_xor(yv, 2);                                       \
                if (q == 0)                                                    \
                    y1T[l * Hd + hh] = make_float2(fmaf(dtv * us, Dv, yv), sdt);\
              } }
        LOADB(b0, 0);
        LOADB(b1, 1); STEPF(b0, 0);
        LOADB(b0, 2); STEPF(b1, 1);
        LOADB(b1, 3); STEPF(b0, 2);
        STEPF(b1, 3);
        #undef STEPF
    } else {
        #define STEPS(buf, bb)                                                 \
            { _Pragma("unroll")                                                \
              for (int k = 0; k < 4; ++k) {                                    \
                int l = lbase + (bb) * 4 + k;                                  \
                float dtv = buf[k].x, us = buf[k].y;                           \
                sdt += dtv;                                                    \
                float yv = 0.f;                                                \
                _Pragma("unroll")                                              \
                for (int jj = 0; jj < 4; ++jj) {                               \
                    float er = __expf(dtv * Are[jj]);                          \
                    float s, cc;                                               \
                    __sincosf(dtv * Aim[jj], &s, &cc);                         \
                    float ar = er * cc, ai = er * s;                           \
                    float gr = fmaf(ar, us, -us);                              \
                    float gi = ai * us;                                        \
                    float nr = fmaf(ar, sr[jj], fmaf(-ai, si[jj],              \
                                 fmaf(gr, BAr[jj], -gi * BAi[jj])));           \
                    float ni = fmaf(ar, si[jj], fmaf( ai, sr[jj],              \
                                 fmaf(gr, BAi[jj],  gi * BAr[jj])));           \
                    sr[jj] = nr; si[jj] = ni;                                  \
                    yv = fmaf(nr, Cre[jj], fmaf(-ni, Cim[jj], yv));            \
                }                                                              \
                yv += __shfl_xor(yv, 1);                                       \
                yv += __shfl_xor(yv, 2);                                       \
                if (q == 0)                                                    \
                    y1T[l * Hd + hh] = make_float2(fmaf(dtv * us, Dv, yv), sdt);\
              } }
        LOADB(b0, 0);
        LOADB(b1, 1); STEPS(b0, 0);
        LOADB(b0, 2); STEPS(b1, 1);
        LOADB(b1, 3); STEPS(b0, 2);
        STEPS(b1, 3);
        #undef STEPS
    }
    #undef LOADB

    int base = c * NCH + hnb;
    #pragma unroll
    for (int jj = 0; jj < 4; ++jj)
        Sb[base + jj] = make_float2(sr[jj], si[jj]);
    if (q == 0) Tc[c * Hd + hh] = sdt;   // same across the quad
}

// ---------------------------------------------------------------------------
// Kernel 3: fused prefix-combine. Block = one h: 16 n-chains x 16 groups.
// Recomputes P = exp(A*Tc) from the scalar Tc (so k_chunk never materializes
// the float4 PS). Emits W[c][chain] = C * h0(c) and Aretab = -exp(A_log).
// ---------------------------------------------------------------------------
__global__ __launch_bounds__(256) void k_comb(const float2* __restrict__ Sb,
        const float* __restrict__ Tc, const float* __restrict__ A_log,
        const float* __restrict__ A_im, const float* __restrict__ C_param,
        float2* __restrict__ W, float* __restrict__ Aretab) {
    __shared__ float4 agg_s[16][NGROUPS + 1];   // [n][g], pad
    __shared__ float Tc_s[NCHUNK];
    const int t = threadIdx.x;
    const int g = t >> 4;                       // 0..15
    const int cl = t & 15;                      // n
    const int h = blockIdx.x;
    const int chain = h * N2d + cl;

    Tc_s[t] = Tc[t * Hd + h];                   // one chunk per thread
    __syncthreads();

    const float Are = -__expf(A_log[chain]);
    const float Aim = A_im[chain];
    if (g == 0) Aretab[chain] = Are;

    float pr[NGRP], pi[NGRP];
    float2 s[NGRP];
    #pragma unroll
    for (int i = 0; i < NGRP; ++i) {
        int c = g * NGRP + i;
        s[i] = Sb[c * NCH + chain];
        float T = Tc_s[c];
        float er = __expf(Are * T);
        float sn, cs;
        __sincosf(Aim * T, &sn, &cs);
        pr[i] = er * cs;
        pi[i] = er * sn;
    }

    float Pr = 1.f, Pi = 0.f, Hr = 0.f, Hi = 0.f;
    #pragma unroll
    for (int i = 0; i < NGRP; ++i) {
        float nhr = fmaf(pr[i], Hr, fmaf(-pi[i], Hi, s[i].x));
        float nhi = fmaf(pr[i], Hi, fmaf( pi[i], Hr, s[i].y));
        float npr = fmaf(pr[i], Pr, -pi[i] * Pi);
        float npi = fmaf(pr[i], Pi,  pi[i] * Pr);
        Hr = nhr; Hi = nhi; Pr = npr; Pi = npi;
    }
    agg_s[cl][g] = make_float4(Pr, Pi, Hr, Hi);
    __syncthreads();

    // exclusive cross-group prefix
    float hr = 0.f, hi = 0.f;
    for (int j = 0; j < g; ++j) {
        float4 a = agg_s[cl][j];
        float nr = fmaf(a.x, hr, fmaf(-a.y, hi, a.z));
        float ni = fmaf(a.x, hi, fmaf( a.y, hr, a.w));
        hr = nr; hi = ni;
    }

    const float Cr = C_param[2 * chain];
    const float Ci = C_param[2 * chain + 1];
    #pragma unroll
    for (int i = 0; i < NGRP; ++i) {
        int c = g * NGRP + i;
        W[c * NCH + chain] = make_float2(fmaf(Cr, hr, -Ci * hi),
                                         fmaf(Cr, hi,  Ci * hr));
        float nr = fmaf(pr[i], hr, fmaf(-pi[i], hi, s[i].x));
        float ni = fmaf(pr[i], hi, fmaf( pi[i], hr, s[i].y));
        hr = nr; hi = ni;
    }
}

// ---------------------------------------------------------------------------
// Kernel 4: correction pass. Thread owns one h (coalesced y1T/out) x 4 l's;
// W row = 128 B contiguous; Are from Aretab (no per-thread exp setup):
//   y = y1 + Re( sum_n exp(A_n*T_l) * W_n )
// ---------------------------------------------------------------------------
__global__ __launch_bounds__(256) void k_corr(const float2* __restrict__ y1T,
        const float* __restrict__ Aretab, const float* __restrict__ A_im,
        const float2* __restrict__ W, float* __restrict__ out) {
    const int t = threadIdx.x;
    const int c = blockIdx.x;        // chunk
    const int hl = t & 63;
    const int h = blockIdx.y * 64 + hl;
    const int lb = t >> 6;           // 0..3
    const int l0 = c * CLEN + lb * 4;
    const int hn0 = h * N2d;

    float2 yt[4];
    #pragma unroll
    for (int k = 0; k < 4; ++k) yt[k] = y1T[(l0 + k) * Hd + h];

    float2 w[N2d];
    #pragma unroll
    for (int n = 0; n < N2d; ++n) w[n] = W[c * NCH + hn0 + n];

    float are[N2d], aim[N2d];
    #pragma unroll
    for (int n = 0; n < N2d; ++n) {
        are[n] = Aretab[hn0 + n];
        aim[n] = A_im[hn0 + n];
    }
    float dA = aim[1] - aim[0];
    bool fast = true;
    #pragma unroll
    for (int n = 1; n < N2d; ++n)
        fast = fast && (are[n] == are[0]) && (aim[n] - aim[n - 1] == dA);

    if (fast) {
        const float Are0 = are[0], Aim0 = aim[0];
        #pragma unroll
        for (int k = 0; k < 4; ++k) {
            float T = yt[k].y;
            float er = __expf(Are0 * T);
            float s0, c0, sd, cd;
            __sincosf(Aim0 * T, &s0, &c0);
            __sincosf(dA * T, &sd, &cd);
            float ar = er * c0, ai = er * s0;
            float corr = 0.f;
            #pragma unroll
            for (int n = 0; n < N2d; ++n) {
                corr = fmaf(ar, w[n].x, fmaf(-ai, w[n].y, corr));
                if (n < N2d - 1) {
                    float tr = fmaf(ar, cd, -ai * sd);
                    ai = fmaf(ai, cd, ar * sd);
                    ar = tr;
                }
            }
            out[(l0 + k) * Hd + h] = yt[k].x + corr;
        }
    } else {
        #pragma unroll
        for (int k = 0; k < 4; ++k) {
            float T = yt[k].y;
            float corr = 0.f;
            #pragma unroll
            for (int n = 0; n < N2d; ++n) {
                float er = __expf(are[n] * T);
                float s, cc;
                __sincosf(aim[n] * T, &s, &cc);
                corr = fmaf(er * cc, w[n].x, fmaf(-er * s, w[n].y, corr));
            }
            out[(l0 + k) * Hd + h] = yt[k].x + corr;
        }
    }
}

extern "C" void kernel_launch(void* const* d_in, const int* in_sizes, int n_in,
                              void* d_out, int out_size, void* d_ws, size_t ws_size,
                              hipStream_t stream) {
    const float* u        = (const float*)d_in[0];
    const float* A_log    = (const float*)d_in[1];
    const float* A_im     = (const float*)d_in[2];
    const float* B_param  = (const float*)d_in[3];
    const float* C_param  = (const float*)d_in[4];
    const float* Dp       = (const float*)d_in[5];
    const float* dt_w     = (const float*)d_in[6];
    const float* dt_b     = (const float*)d_in[7];
    const float* xproj_w  = (const float*)d_in[8];

    // ws layout: du[L*H f2] | Sb[NCHUNK*NCH f2] | W[NCHUNK*NCH f2]
    //          | y1T[L*H f2] | Tc[NCHUNK*Hd f] | Aretab[NCH f]
    float2* du     = (float2*)d_ws;
    float2* Sb     = du + (size_t)Ld * Hd;
    float2* W      = Sb + (size_t)NCHUNK * NCH;
    float2* y1T    = W + (size_t)NCHUNK * NCH;
    float*  Tc     = (float*)(y1T + (size_t)Ld * Hd);
    float*  Aretab = Tc + (size_t)NCHUNK * Hd;
    float*  out    = (float*)d_out;

    k_dt<<<Ld / 8, 256, 0, stream>>>(u, xproj_w, dt_w, dt_b, du);
    dim3 g2(NCHUNK, Hd / 64);
    k_chunk<<<g2, 256, 0, stream>>>(du, A_log, A_im, B_param, C_param, Dp,
                                    Sb, Tc, y1T);
    k_comb<<<Hd, 256, 0, stream>>>(Sb, Tc, A_log, A_im, C_param, W, Aretab);
    k_corr<<<g2, 256, 0, stream>>>(y1T, Aretab, A_im, W, out);
}

// Round 11
// 139.031 us; speedup vs baseline: 1.0126x; 1.0126x over previous
//
#include <hip/hip_runtime.h>

#define Hd 512
#define N2d 16
#define Rd 32
#define Ld 4096
#define NCHUNK 128
#define CLEN (Ld / NCHUNK)        // 32
#define NCH (Hd * N2d)            // 8192 chains
#define NGRP 16                   // chunks per prefix group
#define NGROUPS (NCHUNK / NGRP)   // 8

// ---------------------------------------------------------------------------
// Kernel 1: dt = softplus(u@xprojT@dtwT + b); writes du[l][h] = (dt, u/dt).
// ---------------------------------------------------------------------------
__global__ __launch_bounds__(256) void k_dt(const float* __restrict__ u,
                                            const float* __restrict__ xproj_w,
                                            const float* __restrict__ dt_w,
                                            const float* __restrict__ dt_b,
                                            float2* __restrict__ du_out) {
    __shared__ float u_s[8][Hd];
    __shared__ float dtu_s[8][Rd];
    const int t = threadIdx.x;
    const int l0 = blockIdx.x * 8;

    #pragma unroll
    for (int i = 0; i < 16; ++i) {
        int idx = t + i * 256;
        ((float*)u_s)[idx] = u[l0 * Hd + idx];
    }
    __syncthreads();

    const int r = t >> 3;
    const int j = t & 7;
    float part[8];
    #pragma unroll
    for (int l = 0; l < 8; ++l) part[l] = 0.f;
    for (int k = 0; k < 64; ++k) {
        float w = xproj_w[r * Hd + k * 8 + j];
        #pragma unroll
        for (int l = 0; l < 8; ++l) part[l] = fmaf(u_s[l][k * 8 + j], w, part[l]);
    }
    #pragma unroll
    for (int off = 1; off < 8; off <<= 1) {
        #pragma unroll
        for (int l = 0; l < 8; ++l) part[l] += __shfl_xor(part[l], off);
    }
    if (j == 0) {
        #pragma unroll
        for (int l = 0; l < 8; ++l) dtu_s[l][r] = part[l];
    }
    __syncthreads();

    #pragma unroll
    for (int hb = 0; hb < 2; ++hb) {
        int h = hb * 256 + t;
        float bias = dt_b[h];
        float acc[8];
        #pragma unroll
        for (int l = 0; l < 8; ++l) acc[l] = bias;
        #pragma unroll
        for (int rb = 0; rb < 8; ++rb) {
            float4 w = *(const float4*)&dt_w[h * Rd + rb * 4];
            #pragma unroll
            for (int l = 0; l < 8; ++l) {
                acc[l] = fmaf(dtu_s[l][rb * 4 + 0], w.x, acc[l]);
                acc[l] = fmaf(dtu_s[l][rb * 4 + 1], w.y, acc[l]);
                acc[l] = fmaf(dtu_s[l][rb * 4 + 2], w.z, acc[l]);
                acc[l] = fmaf(dtu_s[l][rb * 4 + 3], w.w, acc[l]);
            }
        }
        #pragma unroll
        for (int l = 0; l < 8; ++l) {
            float x = acc[l];
            float sp = fmaxf(x, 0.f) + log1pf(__expf(-fabsf(x)));  // softplus
            float uv = u_s[l][h];
            float us = uv * __builtin_amdgcn_rcpf(fmaxf(sp, 1e-30f));
            du_out[(l0 + l) * Hd + h] = make_float2(sp, us);
        }
    }
}

// ---------------------------------------------------------------------------
// Kernel 2: per-chunk local scan (h0=0), CLEN=32. 2 n's per thread (8 lanes
// per h) -> grid (128, 16) = 2048 blocks (8 blocks/CU capacity, 2x the TLP of
// the 4-n/4-lane version whose 76 VGPR + 1024-block grid capped latency
// hiding at 4 waves/SIMD). du staged in 8 pipelined batches of 4 (b0/b1
// double buffer, static indexing). Emits:
//   PS[c][chain] = (P.re, P.im, S.re, S.im)
//   y1T[l][h]    = (Re(C*S_local_l) + D*u_l, T_l)
// ---------------------------------------------------------------------------
__global__ __launch_bounds__(256) void k_chunk(const float2* __restrict__ du,
        const float* __restrict__ A_log, const float* __restrict__ A_im,
        const float* __restrict__ B_param, const float* __restrict__ C_param,
        const float* __restrict__ Dp,
        float4* __restrict__ PS, float2* __restrict__ y1T) {
    const int t = threadIdx.x;
    const int q = t & 7;                       // lane within h (8 lanes)
    const int hh = blockIdx.y * 32 + (t >> 3);
    const int c = blockIdx.x;
    const int hnb = hh * N2d + q * 2;          // 2 consecutive n
    const int lbase = c * CLEN;

    float Are[2], Aim[2], BAr[2], BAi[2], Cre[2], Cim[2];
    #pragma unroll
    for (int j = 0; j < 2; ++j) {
        int hn = hnb + j;
        Are[j] = -__expf(A_log[hn]);
        Aim[j] = A_im[hn];
        float Bre = B_param[2 * hn];
        float Bim = B_param[2 * hn + 1];
        float inv = __builtin_amdgcn_rcpf(Are[j] * Are[j] + Aim[j] * Aim[j]);
        BAr[j] = (Bre * Are[j] + Bim * Aim[j]) * inv;   // Bc*conj(A)/|A|^2
        BAi[j] = (Bim * Are[j] - Bre * Aim[j]) * inv;
        Cre[j] = C_param[2 * hn];
        Cim[j] = C_param[2 * hn + 1];
    }
    const bool fast = (Are[1] == Are[0]);
    const float Dv = Dp[hh];

    float sr[2] = {0.f, 0.f}, si[2] = {0.f, 0.f};
    float sdt = 0.f;

    float2 b0[4], b1[4];

    #define LOADB(buf, bb)                                                     \
        { _Pragma("unroll")                                                    \
          for (int k = 0; k < 4; ++k)                                          \
              buf[k] = du[(lbase + (bb) * 4 + k) * Hd + hh]; }

    if (fast) {
        const float Are0 = Are[0], Aim0 = Aim[0], dA = Aim[1] - Aim[0];
        #define STEPF(buf, bb)                                                 \
            { _Pragma("unroll")                                                \
              for (int k = 0; k < 4; ++k) {                                    \
                int l = lbase + (bb) * 4 + k;                                  \
                float dtv = buf[k].x, us = buf[k].y;                           \
                sdt += dtv;                                                    \
                float er = __expf(dtv * Are0);                                 \
                float s0, c0, sd, cd;                                          \
                __sincosf(dtv * Aim0, &s0, &c0);                               \
                __sincosf(dtv * dA, &sd, &cd);                                 \
                float ar = er * c0, ai = er * s0;                              \
                float yv = 0.f;                                                \
                _Pragma("unroll")                                              \
                for (int jj = 0; jj < 2; ++jj) {                               \
                    float gr = fmaf(ar, us, -us);                              \
                    float gi = ai * us;                                        \
                    float nr = fmaf(ar, sr[jj], fmaf(-ai, si[jj],              \
                                 fmaf(gr, BAr[jj], -gi * BAi[jj])));           \
                    float ni = fmaf(ar, si[jj], fmaf( ai, sr[jj],              \
                                 fmaf(gr, BAi[jj],  gi * BAr[jj])));           \
                    sr[jj] = nr; si[jj] = ni;                                  \
                    yv = fmaf(nr, Cre[jj], fmaf(-ni, Cim[jj], yv));            \
                    if (jj < 1) {                                              \
                        float tr = fmaf(ar, cd, -ai * sd);                     \
                        ai = fmaf(ai, cd, ar * sd);                            \
                        ar = tr;                                               \
                    }                                                          \
                }                                                              \
                yv += __shfl_xor(yv, 1);                                       \
                yv += __shfl_xor(yv, 2);                                       \
                yv += __shfl_xor(yv, 4);                                       \
                if (q == 0)                                                    \
                    y1T[l * Hd + hh] = make_float2(fmaf(dtv * us, Dv, yv), sdt);\
              } }
        LOADB(b0, 0);
        LOADB(b1, 1); STEPF(b0, 0);
        LOADB(b0, 2); STEPF(b1, 1);
        LOADB(b1, 3); STEPF(b0, 2);
        LOADB(b0, 4); STEPF(b1, 3);
        LOADB(b1, 5); STEPF(b0, 4);
        LOADB(b0, 6); STEPF(b1, 5);
        LOADB(b1, 7); STEPF(b0, 6);
        STEPF(b1, 7);
        #undef STEPF
    } else {
        #define STEPS(buf, bb)                                                 \
            { _Pragma("unroll")                                                \
              for (int k = 0; k < 4; ++k) {                                    \
                int l = lbase + (bb) * 4 + k;                                  \
                float dtv = buf[k].x, us = buf[k].y;                           \
                sdt += dtv;                                                    \
                float yv = 0.f;                                                \
                _Pragma("unroll")                                              \
                for (int jj = 0; jj < 2; ++jj) {                               \
                    float er = __expf(dtv * Are[jj]);                          \
                    float s, cc;                                               \
                    __sincosf(dtv * Aim[jj], &s, &cc);                         \
                    float ar = er * cc, ai = er * s;                           \
                    float gr = fmaf(ar, us, -us);                              \
                    float gi = ai * us;                                        \
                    float nr = fmaf(ar, sr[jj], fmaf(-ai, si[jj],              \
                                 fmaf(gr, BAr[jj], -gi * BAi[jj])));           \
                    float ni = fmaf(ar, si[jj], fmaf( ai, sr[jj],              \
                                 fmaf(gr, BAi[jj],  gi * BAr[jj])));           \
                    sr[jj] = nr; si[jj] = ni;                                  \
                    yv = fmaf(nr, Cre[jj], fmaf(-ni, Cim[jj], yv));            \
                }                                                              \
                yv += __shfl_xor(yv, 1);                                       \
                yv += __shfl_xor(yv, 2);                                       \
                yv += __shfl_xor(yv, 4);                                       \
                if (q == 0)                                                    \
                    y1T[l * Hd + hh] = make_float2(fmaf(dtv * us, Dv, yv), sdt);\
              } }
        LOADB(b0, 0);
        LOADB(b1, 1); STEPS(b0, 0);
        LOADB(b0, 2); STEPS(b1, 1);
        LOADB(b1, 3); STEPS(b0, 2);
        LOADB(b0, 4); STEPS(b1, 3);
        LOADB(b1, 5); STEPS(b0, 4);
        LOADB(b0, 6); STEPS(b1, 5);
        LOADB(b1, 7); STEPS(b0, 6);
        STEPS(b1, 7);
        #undef STEPS
    }
    #undef LOADB

    int base = c * NCH + hnb;
    #pragma unroll
    for (int jj = 0; jj < 2; ++jj) {
        float er = __expf(sdt * Are[jj]);
        float s, cc;
        __sincosf(sdt * Aim[jj], &s, &cc);
        PS[base + jj] = make_float4(er * cc, er * s, sr[jj], si[jj]);
    }
}

// ---------------------------------------------------------------------------
// Kernel 3: fused prefix-combine. Block = {32 chains x 8 groups} (256 thr).
// Each thread: (1) aggregates its group's 16 PS entries (registers),
// (2) LDS-exchange of the 8 group aggregates per chain + local exclusive
// cross-group prefix, (3) walks its 16 chunks emitting W[c][chain] = C*h0(c).
// ---------------------------------------------------------------------------
__global__ __launch_bounds__(256) void k_comb(const float4* __restrict__ PS,
                                              const float* __restrict__ C_param,
                                              float2* __restrict__ W) {
    __shared__ float4 agg_s[32][NGROUPS + 1];   // [chain_l][g], pad
    const int t = threadIdx.x;
    const int g = t >> 5;                       // 0..7
    const int cl = t & 31;
    const int chain = blockIdx.x * 32 + cl;

    float4 ps[NGRP];
    #pragma unroll
    for (int i = 0; i < NGRP; ++i)
        ps[i] = PS[(g * NGRP + i) * NCH + chain];

    float pr = 1.f, pi = 0.f, hr = 0.f, hi = 0.f;
    #pragma unroll
    for (int i = 0; i < NGRP; ++i) {
        float nhr = fmaf(ps[i].x, hr, fmaf(-ps[i].y, hi, ps[i].z));
        float nhi = fmaf(ps[i].x, hi, fmaf( ps[i].y, hr, ps[i].w));
        float npr = fmaf(ps[i].x, pr, -ps[i].y * pi);
        float npi = fmaf(ps[i].x, pi,  ps[i].y * pr);
        hr = nhr; hi = nhi; pr = npr; pi = npi;
    }
    agg_s[cl][g] = make_float4(pr, pi, hr, hi);
    __syncthreads();

    // exclusive cross-group prefix (g uniform across each 32-lane slice)
    float Hr = 0.f, Hi = 0.f;
    for (int j = 0; j < g; ++j) {
        float4 a = agg_s[cl][j];
        float nr = fmaf(a.x, Hr, fmaf(-a.y, Hi, a.z));
        float ni = fmaf(a.x, Hi, fmaf( a.y, Hr, a.w));
        Hr = nr; Hi = ni;
    }

    const float Cr = C_param[2 * chain];
    const float Ci = C_param[2 * chain + 1];
    #pragma unroll
    for (int i = 0; i < NGRP; ++i) {
        int c = g * NGRP + i;
        W[c * NCH + chain] = make_float2(fmaf(Cr, Hr, -Ci * Hi),
                                         fmaf(Cr, Hi,  Ci * Hr));
        float nr = fmaf(ps[i].x, Hr, fmaf(-ps[i].y, Hi, ps[i].z));
        float ni = fmaf(ps[i].x, Hi, fmaf( ps[i].y, Hr, ps[i].w));
        Hr = nr; Hi = ni;
    }
}

// ---------------------------------------------------------------------------
// Kernel 4: correction pass. No LDS, no sync. Thread owns one h (coalesced
// y1T/out) x 8 l's; reads its W row (128 B contiguous) and A rows (L2-hot):
//   y = y1 + Re( sum_n exp(A_n*T_l) * W_n )
// ---------------------------------------------------------------------------
__global__ __launch_bounds__(256) void k_corr(const float2* __restrict__ y1T,
        const float* __restrict__ A_log, const float* __restrict__ A_im,
        const float2* __restrict__ W, float* __restrict__ out) {
    const int t = threadIdx.x;
    const int c = blockIdx.x;        // chunk
    const int hl = t & 63;
    const int h = blockIdx.y * 64 + hl;
    const int lb = t >> 6;           // 0..3
    const int l0 = c * CLEN + lb * 8;
    const int hn0 = h * N2d;

    float2 yt[8];
    #pragma unroll
    for (int k = 0; k < 8; ++k) yt[k] = y1T[(l0 + k) * Hd + h];

    float2 w[N2d];
    #pragma unroll
    for (int n = 0; n < N2d; ++n) w[n] = W[c * NCH + hn0 + n];

    float are[N2d], aim[N2d];
    #pragma unroll
    for (int n = 0; n < N2d; ++n) {
        are[n] = -__expf(A_log[hn0 + n]);
        aim[n] = A_im[hn0 + n];
    }
    float dA = aim[1] - aim[0];
    bool fast = true;
    #pragma unroll
    for (int n = 1; n < N2d; ++n)
        fast = fast && (are[n] == are[0]) && (aim[n] - aim[n - 1] == dA);

    if (fast) {
        const float Are0 = are[0], Aim0 = aim[0];
        #pragma unroll
        for (int k = 0; k < 8; ++k) {
            float T = yt[k].y;
            float er = __expf(Are0 * T);
            float s0, c0, sd, cd;
            __sincosf(Aim0 * T, &s0, &c0);
            __sincosf(dA * T, &sd, &cd);
            float ar = er * c0, ai = er * s0;
            float corr = 0.f;
            #pragma unroll
            for (int n = 0; n < N2d; ++n) {
                corr = fmaf(ar, w[n].x, fmaf(-ai, w[n].y, corr));
                if (n < N2d - 1) {
                    float tr = fmaf(ar, cd, -ai * sd);
                    ai = fmaf(ai, cd, ar * sd);
                    ar = tr;
                }
            }
            out[(l0 + k) * Hd + h] = yt[k].x + corr;
        }
    } else {
        #pragma unroll
        for (int k = 0; k < 8; ++k) {
            float T = yt[k].y;
            float corr = 0.f;
            #pragma unroll
            for (int n = 0; n < N2d; ++n) {
                float er = __expf(are[n] * T);
                float s, cc;
                __sincosf(aim[n] * T, &s, &cc);
                corr = fmaf(er * cc, w[n].x, fmaf(-er * s, w[n].y, corr));
            }
            out[(l0 + k) * Hd + h] = yt[k].x + corr;
        }
    }
}

extern "C" void kernel_launch(void* const* d_in, const int* in_sizes, int n_in,
                              void* d_out, int out_size, void* d_ws, size_t ws_size,
                              hipStream_t stream) {
    const float* u        = (const float*)d_in[0];
    const float* A_log    = (const float*)d_in[1];
    const float* A_im     = (const float*)d_in[2];
    const float* B_param  = (const float*)d_in[3];
    const float* C_param  = (const float*)d_in[4];
    const float* Dp       = (const float*)d_in[5];
    const float* dt_w     = (const float*)d_in[6];
    const float* dt_b     = (const float*)d_in[7];
    const float* xproj_w  = (const float*)d_in[8];

    // ws layout: du[L*H f2] | PS[NCHUNK*NCH f4] | W[NCHUNK*NCH f2] | y1T[L*H f2]
    float2* du  = (float2*)d_ws;
    float4* PS  = (float4*)(du + (size_t)Ld * Hd);
    float2* W   = (float2*)(PS + (size_t)NCHUNK * NCH);
    float2* y1T = W + (size_t)NCHUNK * NCH;
    float*  out = (float*)d_out;

    k_dt<<<Ld / 8, 256, 0, stream>>>(u, xproj_w, dt_w, dt_b, du);
    dim3 gc(NCHUNK, Hd / 32);
    k_chunk<<<gc, 256, 0, stream>>>(du, A_log, A_im, B_param, C_param, Dp,
                                    PS, y1T);
    k_comb<<<NCH / 32, 256, 0, stream>>>(PS, C_param, W);
    dim3 gr(NCHUNK, Hd / 64);
    k_corr<<<gr, 256, 0, stream>>>(y1T, A_log, A_im, W, out);
}

// Round 12
// 137.160 us; speedup vs baseline: 1.0264x; 1.0136x over previous
//
#include <hip/hip_runtime.h>

#define Hd 512
#define N2d 16
#define Rd 32
#define Ld 4096
#define NCHUNK 128
#define CLEN (Ld / NCHUNK)        // 32
#define NCH (Hd * N2d)            // 8192 chains
#define NGRP 16                   // chunks per prefix group
#define NGROUPS (NCHUNK / NGRP)   // 8

// ---------------------------------------------------------------------------
// Kernel 1: dt = softplus(u@xprojT@dtwT + b); writes du[l][h] = (dt, u/dt).
// ---------------------------------------------------------------------------
__global__ __launch_bounds__(256) void k_dt(const float* __restrict__ u,
                                            const float* __restrict__ xproj_w,
                                            const float* __restrict__ dt_w,
                                            const float* __restrict__ dt_b,
                                            float2* __restrict__ du_out) {
    __shared__ float u_s[8][Hd];
    __shared__ float dtu_s[8][Rd];
    const int t = threadIdx.x;
    const int l0 = blockIdx.x * 8;

    #pragma unroll
    for (int i = 0; i < 16; ++i) {
        int idx = t + i * 256;
        ((float*)u_s)[idx] = u[l0 * Hd + idx];
    }
    __syncthreads();

    const int r = t >> 3;
    const int j = t & 7;
    float part[8];
    #pragma unroll
    for (int l = 0; l < 8; ++l) part[l] = 0.f;
    for (int k = 0; k < 64; ++k) {
        float w = xproj_w[r * Hd + k * 8 + j];
        #pragma unroll
        for (int l = 0; l < 8; ++l) part[l] = fmaf(u_s[l][k * 8 + j], w, part[l]);
    }
    #pragma unroll
    for (int off = 1; off < 8; off <<= 1) {
        #pragma unroll
        for (int l = 0; l < 8; ++l) part[l] += __shfl_xor(part[l], off);
    }
    if (j == 0) {
        #pragma unroll
        for (int l = 0; l < 8; ++l) dtu_s[l][r] = part[l];
    }
    __syncthreads();

    #pragma unroll
    for (int hb = 0; hb < 2; ++hb) {
        int h = hb * 256 + t;
        float bias = dt_b[h];
        float acc[8];
        #pragma unroll
        for (int l = 0; l < 8; ++l) acc[l] = bias;
        #pragma unroll
        for (int rb = 0; rb < 8; ++rb) {
            float4 w = *(const float4*)&dt_w[h * Rd + rb * 4];
            #pragma unroll
            for (int l = 0; l < 8; ++l) {
                acc[l] = fmaf(dtu_s[l][rb * 4 + 0], w.x, acc[l]);
                acc[l] = fmaf(dtu_s[l][rb * 4 + 1], w.y, acc[l]);
                acc[l] = fmaf(dtu_s[l][rb * 4 + 2], w.z, acc[l]);
                acc[l] = fmaf(dtu_s[l][rb * 4 + 3], w.w, acc[l]);
            }
        }
        #pragma unroll
        for (int l = 0; l < 8; ++l) {
            float x = acc[l];
            float sp = fmaxf(x, 0.f) + log1pf(__expf(-fabsf(x)));  // softplus
            float uv = u_s[l][h];
            float us = uv * __builtin_amdgcn_rcpf(fmaxf(sp, 1e-30f));
            du_out[(l0 + l) * Hd + h] = make_float2(sp, us);
        }
    }
}

// ---------------------------------------------------------------------------
// Kernel 2: per-chunk local scan (h0=0), CLEN=32, 4 n per thread (r9 geometry
// — r10/r11 showed 16-step chunks and 2n/8lane splits both lose). CHANGE vs
// r9: the block's 16 KB du tile is cooperatively staged into LDS once
// (coalesced float4), replacing 4x-redundant per-quad global loads + 16 VGPRs
// of register staging. Quad-uniform LDS reads broadcast for free; 16 distinct
// h per wave hit distinct banks. Emits:
//   PS[c][chain] = (P.re, P.im, S.re, S.im)
//   y1T[l][h]    = (Re(C*S_local_l) + D*u_l, T_l)
// ---------------------------------------------------------------------------
__global__ __launch_bounds__(256) void k_chunk(const float2* __restrict__ du,
        const float* __restrict__ A_log, const float* __restrict__ A_im,
        const float* __restrict__ B_param, const float* __restrict__ C_param,
        const float* __restrict__ Dp,
        float4* __restrict__ PS, float2* __restrict__ y1T) {
    __shared__ float2 du_s[CLEN][64];          // 16 KB
    const int t = threadIdx.x;
    const int q = t & 3;
    const int hl = t >> 2;                     // 0..63
    const int hh = blockIdx.y * 64 + hl;
    const int c = blockIdx.x;
    const int hnb = hh * N2d + q * 4;
    const int lbase = c * CLEN;

    // ---- cooperative stage: 32 rows x 512 B, coalesced float4 ----
    {
        const float2* base = du + (size_t)lbase * Hd + blockIdx.y * 64;
        #pragma unroll
        for (int i = 0; i < 4; ++i) {
            int idx = i * 256 + t;             // 0..1023
            int row = idx >> 5;                // 32 float4 per row
            int c4  = idx & 31;
            const float4* srcrow = reinterpret_cast<const float4*>(base + (size_t)row * Hd);
            ((float4*)du_s)[idx] = srcrow[c4];
        }
    }

    // ---- per-thread constants (uniformity checked on raw A_log: fast path
    //      needs only ONE exp instead of four) ----
    float alog[4], Aim[4];
    #pragma unroll
    for (int j = 0; j < 4; ++j) {
        alog[j] = A_log[hnb + j];
        Aim[j] = A_im[hnb + j];
    }
    float d1 = Aim[1] - Aim[0], d2 = Aim[2] - Aim[1], d3 = Aim[3] - Aim[2];
    const bool fast = (alog[1] == alog[0]) && (alog[2] == alog[0]) &&
                      (alog[3] == alog[0]) && (d1 == d2) && (d2 == d3);
    float Are[4], BAr[4], BAi[4], Cre[4], Cim[4];
    Are[0] = -__expf(alog[0]);
    #pragma unroll
    for (int j = 1; j < 4; ++j)
        Are[j] = fast ? Are[0] : -__expf(alog[j]);
    #pragma unroll
    for (int j = 0; j < 4; ++j) {
        int hn = hnb + j;
        float Bre = B_param[2 * hn];
        float Bim = B_param[2 * hn + 1];
        float inv = __builtin_amdgcn_rcpf(Are[j] * Are[j] + Aim[j] * Aim[j]);
        BAr[j] = (Bre * Are[j] + Bim * Aim[j]) * inv;   // Bc*conj(A)/|A|^2
        BAi[j] = (Bim * Are[j] - Bre * Aim[j]) * inv;
        Cre[j] = C_param[2 * hn];
        Cim[j] = C_param[2 * hn + 1];
    }
    const float Dv = Dp[hh];

    __syncthreads();

    float sr[4] = {0.f, 0.f, 0.f, 0.f}, si[4] = {0.f, 0.f, 0.f, 0.f};
    float sdt = 0.f;

    if (fast) {
        const float Are0 = Are[0], Aim0 = Aim[0], dA = Aim[1] - Aim[0];
        #pragma unroll
        for (int k = 0; k < CLEN; ++k) {
            float2 d = du_s[k][hl];
            float dtv = d.x, us = d.y;
            sdt += dtv;                        // inclusive T_l
            float er = __expf(dtv * Are0);
            float s0, c0, sd, cd;
            __sincosf(dtv * Aim0, &s0, &c0);
            __sincosf(dtv * dA, &sd, &cd);
            float ar = er * c0, ai = er * s0;
            float yv = 0.f;
            #pragma unroll
            for (int jj = 0; jj < 4; ++jj) {
                float gr = fmaf(ar, us, -us);
                float gi = ai * us;
                float nr = fmaf(ar, sr[jj], fmaf(-ai, si[jj], fmaf(gr, BAr[jj], -gi * BAi[jj])));
                float ni = fmaf(ar, si[jj], fmaf( ai, sr[jj], fmaf(gr, BAi[jj],  gi * BAr[jj])));
                sr[jj] = nr; si[jj] = ni;
                yv = fmaf(nr, Cre[jj], fmaf(-ni, Cim[jj], yv));
                if (jj < 3) {
                    float tr = fmaf(ar, cd, -ai * sd);
                    ai = fmaf(ai, cd, ar * sd);
                    ar = tr;
                }
            }
            yv += __shfl_xor(yv, 1);
            yv += __shfl_xor(yv, 2);
            if (q == 0)
                y1T[(lbase + k) * Hd + hh] = make_float2(fmaf(dtv * us, Dv, yv), sdt);
        }
    } else {
        #pragma unroll
        for (int k = 0; k < CLEN; ++k) {
            float2 d = du_s[k][hl];
            float dtv = d.x, us = d.y;
            sdt += dtv;
            float yv = 0.f;
            #pragma unroll
            for (int jj = 0; jj < 4; ++jj) {
                float er = __expf(dtv * Are[jj]);
                float s, cc;
                __sincosf(dtv * Aim[jj], &s, &cc);
                float ar = er * cc, ai = er * s;
                float gr = fmaf(ar, us, -us);
                float gi = ai * us;
                float nr = fmaf(ar, sr[jj], fmaf(-ai, si[jj], fmaf(gr, BAr[jj], -gi * BAi[jj])));
                float ni = fmaf(ar, si[jj], fmaf( ai, sr[jj], fmaf(gr, BAi[jj],  gi * BAr[jj])));
                sr[jj] = nr; si[jj] = ni;
                yv = fmaf(nr, Cre[jj], fmaf(-ni, Cim[jj], yv));
            }
            yv += __shfl_xor(yv, 1);
            yv += __shfl_xor(yv, 2);
            if (q == 0)
                y1T[(lbase + k) * Hd + hh] = make_float2(fmaf(dtv * us, Dv, yv), sdt);
        }
    }

    int base = c * NCH + hnb;
    #pragma unroll
    for (int jj = 0; jj < 4; ++jj) {
        float er = __expf(sdt * Are[jj]);
        float s, cc;
        __sincosf(sdt * Aim[jj], &s, &cc);
        PS[base + jj] = make_float4(er * cc, er * s, sr[jj], si[jj]);
    }
}

// ---------------------------------------------------------------------------
// Kernel 3: fused prefix-combine. Block = {32 chains x 8 groups} (256 thr).
// Each thread: (1) aggregates its group's 16 PS entries (registers),
// (2) LDS-exchange of the 8 group aggregates per chain + local exclusive
// cross-group prefix, (3) walks its 16 chunks emitting W[c][chain] = C*h0(c).
// ---------------------------------------------------------------------------
__global__ __launch_bounds__(256) void k_comb(const float4* __restrict__ PS,
                                              const float* __restrict__ C_param,
                                              float2* __restrict__ W) {
    __shared__ float4 agg_s[32][NGROUPS + 1];   // [chain_l][g], pad
    const int t = threadIdx.x;
    const int g = t >> 5;                       // 0..7
    const int cl = t & 31;
    const int chain = blockIdx.x * 32 + cl;

    float4 ps[NGRP];
    #pragma unroll
    for (int i = 0; i < NGRP; ++i)
        ps[i] = PS[(g * NGRP + i) * NCH + chain];

    float pr = 1.f, pi = 0.f, hr = 0.f, hi = 0.f;
    #pragma unroll
    for (int i = 0; i < NGRP; ++i) {
        float nhr = fmaf(ps[i].x, hr, fmaf(-ps[i].y, hi, ps[i].z));
        float nhi = fmaf(ps[i].x, hi, fmaf( ps[i].y, hr, ps[i].w));
        float npr = fmaf(ps[i].x, pr, -ps[i].y * pi);
        float npi = fmaf(ps[i].x, pi,  ps[i].y * pr);
        hr = nhr; hi = nhi; pr = npr; pi = npi;
    }
    agg_s[cl][g] = make_float4(pr, pi, hr, hi);
    __syncthreads();

    // exclusive cross-group prefix (g uniform across each 32-lane slice)
    float Hr = 0.f, Hi = 0.f;
    for (int j = 0; j < g; ++j) {
        float4 a = agg_s[cl][j];
        float nr = fmaf(a.x, Hr, fmaf(-a.y, Hi, a.z));
        float ni = fmaf(a.x, Hi, fmaf( a.y, Hr, a.w));
        Hr = nr; Hi = ni;
    }

    const float Cr = C_param[2 * chain];
    const float Ci = C_param[2 * chain + 1];
    #pragma unroll
    for (int i = 0; i < NGRP; ++i) {
        int c = g * NGRP + i;
        W[c * NCH + chain] = make_float2(fmaf(Cr, Hr, -Ci * Hi),
                                         fmaf(Cr, Hi,  Ci * Hr));
        float nr = fmaf(ps[i].x, Hr, fmaf(-ps[i].y, Hi, ps[i].z));
        float ni = fmaf(ps[i].x, Hi, fmaf( ps[i].y, Hr, ps[i].w));
        Hr = nr; Hi = ni;
    }
}

// ---------------------------------------------------------------------------
// Kernel 4: correction pass. No LDS, no sync. Thread owns one h (coalesced
// y1T/out) x 8 l's; reads its W row (128 B contiguous) and A rows (L2-hot):
//   y = y1 + Re( sum_n exp(A_n*T_l) * W_n )
// ---------------------------------------------------------------------------
__global__ __launch_bounds__(256) void k_corr(const float2* __restrict__ y1T,
        const float* __restrict__ A_log, const float* __restrict__ A_im,
        const float2* __restrict__ W, float* __restrict__ out) {
    const int t = threadIdx.x;
    const int c = blockIdx.x;        // chunk
    const int hl = t & 63;
    const int h = blockIdx.y * 64 + hl;
    const int lb = t >> 6;           // 0..3
    const int l0 = c * CLEN + lb * 8;
    const int hn0 = h * N2d;

    float2 yt[8];
    #pragma unroll
    for (int k = 0; k < 8; ++k) yt[k] = y1T[(l0 + k) * Hd + h];

    float2 w[N2d];
    #pragma unroll
    for (int n = 0; n < N2d; ++n) w[n] = W[c * NCH + hn0 + n];

    float are[N2d], aim[N2d];
    #pragma unroll
    for (int n = 0; n < N2d; ++n) {
        are[n] = -__expf(A_log[hn0 + n]);
        aim[n] = A_im[hn0 + n];
    }
    float dA = aim[1] - aim[0];
    bool fast = true;
    #pragma unroll
    for (int n = 1; n < N2d; ++n)
        fast = fast && (are[n] == are[0]) && (aim[n] - aim[n - 1] == dA);

    if (fast) {
        const float Are0 = are[0], Aim0 = aim[0];
        #pragma unroll
        for (int k = 0; k < 8; ++k) {
            float T = yt[k].y;
            float er = __expf(Are0 * T);
            float s0, c0, sd, cd;
            __sincosf(Aim0 * T, &s0, &c0);
            __sincosf(dA * T, &sd, &cd);
            float ar = er * c0, ai = er * s0;
            float corr = 0.f;
            #pragma unroll
            for (int n = 0; n < N2d; ++n) {
                corr = fmaf(ar, w[n].x, fmaf(-ai, w[n].y, corr));
                if (n < N2d - 1) {
                    float tr = fmaf(ar, cd, -ai * sd);
                    ai = fmaf(ai, cd, ar * sd);
                    ar = tr;
                }
            }
            out[(l0 + k) * Hd + h] = yt[k].x + corr;
        }
    } else {
        #pragma unroll
        for (int k = 0; k < 8; ++k) {
            float T = yt[k].y;
            float corr = 0.f;
            #pragma unroll
            for (int n = 0; n < N2d; ++n) {
                float er = __expf(are[n] * T);
                float s, cc;
                __sincosf(aim[n] * T, &s, &cc);
                corr = fmaf(er * cc, w[n].x, fmaf(-er * s, w[n].y, corr));
            }
            out[(l0 + k) * Hd + h] = yt[k].x + corr;
        }
    }
}

extern "C" void kernel_launch(void* const* d_in, const int* in_sizes, int n_in,
                              void* d_out, int out_size, void* d_ws, size_t ws_size,
                              hipStream_t stream) {
    const float* u        = (const float*)d_in[0];
    const float* A_log    = (const float*)d_in[1];
    const float* A_im     = (const float*)d_in[2];
    const float* B_param  = (const float*)d_in[3];
    const float* C_param  = (const float*)d_in[4];
    const float* Dp       = (const float*)d_in[5];
    const float* dt_w     = (const float*)d_in[6];
    const float* dt_b     = (const float*)d_in[7];
    const float* xproj_w  = (const float*)d_in[8];

    // ws layout: du[L*H f2] | PS[NCHUNK*NCH f4] | W[NCHUNK*NCH f2] | y1T[L*H f2]
    float2* du  = (float2*)d_ws;
    float4* PS  = (float4*)(du + (size_t)Ld * Hd);
    float2* W   = (float2*)(PS + (size_t)NCHUNK * NCH);
    float2* y1T = W + (size_t)NCHUNK * NCH;
    float*  out = (float*)d_out;

    k_dt<<<Ld / 8, 256, 0, stream>>>(u, xproj_w, dt_w, dt_b, du);
    dim3 g2(NCHUNK, Hd / 64);
    k_chunk<<<g2, 256, 0, stream>>>(du, A_log, A_im, B_param, C_param, Dp,
                                    PS, y1T);
    k_comb<<<NCH / 32, 256, 0, stream>>>(PS, C_param, W);
    k_corr<<<g2, 256, 0, stream>>>(y1T, A_log, A_im, W, out);
}

// Round 13
// 132.141 us; speedup vs baseline: 1.0654x; 1.0380x over previous
//
#include <hip/hip_runtime.h>

#define Hd 512
#define N2d 16
#define Rd 32
#define Ld 4096
#define NCHUNK 128
#define CLEN (Ld / NCHUNK)        // 32
#define NCH (Hd * N2d)            // 8192 chains
#define NGRP 16                   // chunks per prefix group
#define NGROUPS (NCHUNK / NGRP)   // 8

// ---------------------------------------------------------------------------
// Kernel 1: dt = softplus(u@xprojT@dtwT + b); writes du[l][h] = (dt, u/dt).
// ---------------------------------------------------------------------------
__global__ __launch_bounds__(256) void k_dt(const float* __restrict__ u,
                                            const float* __restrict__ xproj_w,
                                            const float* __restrict__ dt_w,
                                            const float* __restrict__ dt_b,
                                            float2* __restrict__ du_out) {
    __shared__ float u_s[8][Hd];
    __shared__ float dtu_s[8][Rd];
    const int t = threadIdx.x;
    const int l0 = blockIdx.x * 8;

    #pragma unroll
    for (int i = 0; i < 16; ++i) {
        int idx = t + i * 256;
        ((float*)u_s)[idx] = u[l0 * Hd + idx];
    }
    __syncthreads();

    const int r = t >> 3;
    const int j = t & 7;
    float part[8];
    #pragma unroll
    for (int l = 0; l < 8; ++l) part[l] = 0.f;
    for (int k = 0; k < 64; ++k) {
        float w = xproj_w[r * Hd + k * 8 + j];
        #pragma unroll
        for (int l = 0; l < 8; ++l) part[l] = fmaf(u_s[l][k * 8 + j], w, part[l]);
    }
    #pragma unroll
    for (int off = 1; off < 8; off <<= 1) {
        #pragma unroll
        for (int l = 0; l < 8; ++l) part[l] += __shfl_xor(part[l], off);
    }
    if (j == 0) {
        #pragma unroll
        for (int l = 0; l < 8; ++l) dtu_s[l][r] = part[l];
    }
    __syncthreads();

    #pragma unroll
    for (int hb = 0; hb < 2; ++hb) {
        int h = hb * 256 + t;
        float bias = dt_b[h];
        float acc[8];
        #pragma unroll
        for (int l = 0; l < 8; ++l) acc[l] = bias;
        #pragma unroll
        for (int rb = 0; rb < 8; ++rb) {
            float4 w = *(const float4*)&dt_w[h * Rd + rb * 4];
            #pragma unroll
            for (int l = 0; l < 8; ++l) {
                acc[l] = fmaf(dtu_s[l][rb * 4 + 0], w.x, acc[l]);
                acc[l] = fmaf(dtu_s[l][rb * 4 + 1], w.y, acc[l]);
                acc[l] = fmaf(dtu_s[l][rb * 4 + 2], w.z, acc[l]);
                acc[l] = fmaf(dtu_s[l][rb * 4 + 3], w.w, acc[l]);
            }
        }
        #pragma unroll
        for (int l = 0; l < 8; ++l) {
            float x = acc[l];
            float sp = fmaxf(x, 0.f) + log1pf(__expf(-fabsf(x)));  // softplus
            float uv = u_s[l][h];
            float us = uv * __builtin_amdgcn_rcpf(fmaxf(sp, 1e-30f));
            du_out[(l0 + l) * Hd + h] = make_float2(sp, us);
        }
    }
}

// ---------------------------------------------------------------------------
// Kernel 2: per-chunk local scan (h0=0), r9 geometry (CLEN=32, 4 n/thread,
// register double-buffered staging — r10/r11/r12 alternatives all lost).
// CHANGE vs r9: emits Sb (float2) + Tc (scalar chunk dt-sum) instead of the
// float4 PS — P = exp(A*Tc) is recomputed in k_comb from the SAME sdt, so
// results are bit-identical while the PS round-trip (-33.6 MB HBM) vanishes.
//   y1T[l][h] = (Re(C*S_local_l) + D*u_l, T_l)   (unchanged)
// ---------------------------------------------------------------------------
__global__ __launch_bounds__(256) void k_chunk(const float2* __restrict__ du,
        const float* __restrict__ A_log, const float* __restrict__ A_im,
        const float* __restrict__ B_param, const float* __restrict__ C_param,
        const float* __restrict__ Dp,
        float2* __restrict__ Sb, float* __restrict__ Tc,
        float2* __restrict__ y1T) {
    const int t = threadIdx.x;
    const int q = t & 3;
    const int hh = blockIdx.y * 64 + (t >> 2);
    const int c = blockIdx.x;
    const int hnb = hh * N2d + q * 4;
    const int lbase = c * CLEN;

    float alog[4], Aim[4];
    #pragma unroll
    for (int j = 0; j < 4; ++j) {
        alog[j] = A_log[hnb + j];
        Aim[j] = A_im[hnb + j];
    }
    float d1 = Aim[1] - Aim[0], d2 = Aim[2] - Aim[1], d3 = Aim[3] - Aim[2];
    const bool fast = (alog[1] == alog[0]) && (alog[2] == alog[0]) &&
                      (alog[3] == alog[0]) && (d1 == d2) && (d2 == d3);
    float Are[4];
    if (fast) {                     // branch (not ternary) so 3 exps vanish
        Are[0] = -__expf(alog[0]);
        Are[1] = Are[2] = Are[3] = Are[0];
    } else {
        #pragma unroll
        for (int j = 0; j < 4; ++j) Are[j] = -__expf(alog[j]);
    }
    float BAr[4], BAi[4], Cre[4], Cim[4];
    #pragma unroll
    for (int j = 0; j < 4; ++j) {
        int hn = hnb + j;
        float Bre = B_param[2 * hn];
        float Bim = B_param[2 * hn + 1];
        float inv = __builtin_amdgcn_rcpf(Are[j] * Are[j] + Aim[j] * Aim[j]);
        BAr[j] = (Bre * Are[j] + Bim * Aim[j]) * inv;   // Bc*conj(A)/|A|^2
        BAi[j] = (Bim * Are[j] - Bre * Aim[j]) * inv;
        Cre[j] = C_param[2 * hn];
        Cim[j] = C_param[2 * hn + 1];
    }
    const float Dv = Dp[hh];

    float sr[4] = {0.f, 0.f, 0.f, 0.f}, si[4] = {0.f, 0.f, 0.f, 0.f};
    float sdt = 0.f;

    float2 b0[8], b1[8];

    #define LOADB(buf, bb)                                                     \
        { _Pragma("unroll")                                                    \
          for (int k = 0; k < 8; ++k)                                          \
              buf[k] = du[(lbase + (bb) * 8 + k) * Hd + hh]; }

    if (fast) {
        const float Are0 = Are[0], Aim0 = Aim[0], dA = Aim[1] - Aim[0];
        #define STEPF(buf, bb)                                                 \
            { _Pragma("unroll")                                                \
              for (int k = 0; k < 8; ++k) {                                    \
                int l = lbase + (bb) * 8 + k;                                  \
                float dtv = buf[k].x, us = buf[k].y;                           \
                sdt += dtv;                                                    \
                float er = __expf(dtv * Are0);                                 \
                float s0, c0, sd, cd;                                          \
                __sincosf(dtv * Aim0, &s0, &c0);                               \
                __sincosf(dtv * dA, &sd, &cd);                                 \
                float ar = er * c0, ai = er * s0;                              \
                float yv = 0.f;                                                \
                _Pragma("unroll")                                              \
                for (int jj = 0; jj < 4; ++jj) {                               \
                    float gr = fmaf(ar, us, -us);                              \
                    float gi = ai * us;                                        \
                    float nr = fmaf(ar, sr[jj], fmaf(-ai, si[jj],              \
                                 fmaf(gr, BAr[jj], -gi * BAi[jj])));           \
                    float ni = fmaf(ar, si[jj], fmaf( ai, sr[jj],              \
                                 fmaf(gr, BAi[jj],  gi * BAr[jj])));           \
                    sr[jj] = nr; si[jj] = ni;                                  \
                    yv = fmaf(nr, Cre[jj], fmaf(-ni, Cim[jj], yv));            \
                    if (jj < 3) {                                              \
                        float tr = fmaf(ar, cd, -ai * sd);                     \
                        ai = fmaf(ai, cd, ar * sd);                            \
                        ar = tr;                                               \
                    }                                                          \
                }                                                              \
                yv += __shfl_xor(yv, 1);                                       \
                yv += __shfl_xor(yv, 2);                                       \
                if (q == 0)                                                    \
                    y1T[l * Hd + hh] = make_float2(fmaf(dtv * us, Dv, yv), sdt);\
              } }
        LOADB(b0, 0);
        LOADB(b1, 1); STEPF(b0, 0);
        LOADB(b0, 2); STEPF(b1, 1);
        LOADB(b1, 3); STEPF(b0, 2);
        STEPF(b1, 3);
        #undef STEPF
    } else {
        #define STEPS(buf, bb)                                                 \
            { _Pragma("unroll")                                                \
              for (int k = 0; k < 8; ++k) {                                    \
                int l = lbase + (bb) * 8 + k;                                  \
                float dtv = buf[k].x, us = buf[k].y;                           \
                sdt += dtv;                                                    \
                float yv = 0.f;                                                \
                _Pragma("unroll")                                              \
                for (int jj = 0; jj < 4; ++jj) {                               \
                    float er = __expf(dtv * Are[jj]);                          \
                    float s, cc;                                               \
                    __sincosf(dtv * Aim[jj], &s, &cc);                         \
                    float ar = er * cc, ai = er * s;                           \
                    float gr = fmaf(ar, us, -us);                              \
                    float gi = ai * us;                                        \
                    float nr = fmaf(ar, sr[jj], fmaf(-ai, si[jj],              \
                                 fmaf(gr, BAr[jj], -gi * BAi[jj])));           \
                    float ni = fmaf(ar, si[jj], fmaf( ai, sr[jj],              \
                                 fmaf(gr, BAi[jj],  gi * BAr[jj])));           \
                    sr[jj] = nr; si[jj] = ni;                                  \
                    yv = fmaf(nr, Cre[jj], fmaf(-ni, Cim[jj], yv));            \
                }                                                              \
                yv += __shfl_xor(yv, 1);                                       \
                yv += __shfl_xor(yv, 2);                                       \
                if (q == 0)                                                    \
                    y1T[l * Hd + hh] = make_float2(fmaf(dtv * us, Dv, yv), sdt);\
              } }
        LOADB(b0, 0);
        LOADB(b1, 1); STEPS(b0, 0);
        LOADB(b0, 2); STEPS(b1, 1);
        LOADB(b1, 3); STEPS(b0, 2);
        STEPS(b1, 3);
        #undef STEPS
    }
    #undef LOADB

    int base = c * NCH + hnb;
    #pragma unroll
    for (int jj = 0; jj < 4; ++jj)
        Sb[base + jj] = make_float2(sr[jj], si[jj]);
    if (q == 0) Tc[hh * NCHUNK + c] = sdt;   // [h][c] layout (coalesced reload)
}

// ---------------------------------------------------------------------------
// Kernel 3: fused prefix-combine. Block = {32 chains x 8 groups} (256 thr).
// P = exp(A*Tc) recomputed from the scalar Tc (bit-identical to the old
// materialized PS: same sdt, same exp/sincos). Tc staged in LDS (block spans
// exactly 2 h). Emits W[c][chain] = C * h0(c).
// ---------------------------------------------------------------------------
__global__ __launch_bounds__(256) void k_comb(const float2* __restrict__ Sb,
        const float* __restrict__ Tc, const float* __restrict__ A_log,
        const float* __restrict__ A_im, const float* __restrict__ C_param,
        float2* __restrict__ W) {
    __shared__ float4 agg_s[32][NGROUPS + 1];   // [chain_l][g], pad
    __shared__ float Tc_s[2][NCHUNK];
    const int t = threadIdx.x;
    const int g = t >> 5;                       // 0..7
    const int cl = t & 31;
    const int chain = blockIdx.x * 32 + cl;
    const int h0 = blockIdx.x * 2;              // block spans h0, h0+1

    {
        int cc = t & 127;
        int hs = t >> 7;
        Tc_s[hs][cc] = Tc[(h0 + hs) * NCHUNK + cc];
    }
    __syncthreads();

    const int hsel = cl >> 4;
    const float Are = -__expf(A_log[chain]);
    const float Aim = A_im[chain];

    float2 s[NGRP];
    float pr[NGRP], pi[NGRP];
    #pragma unroll
    for (int i = 0; i < NGRP; ++i) {
        int c = g * NGRP + i;
        s[i] = Sb[c * NCH + chain];
        float T = Tc_s[hsel][c];
        float er = __expf(Are * T);
        float sn, cs;
        __sincosf(Aim * T, &sn, &cs);
        pr[i] = er * cs;
        pi[i] = er * sn;
    }

    float Pr = 1.f, Pi = 0.f, Hr = 0.f, Hi = 0.f;
    #pragma unroll
    for (int i = 0; i < NGRP; ++i) {
        float nhr = fmaf(pr[i], Hr, fmaf(-pi[i], Hi, s[i].x));
        float nhi = fmaf(pr[i], Hi, fmaf( pi[i], Hr, s[i].y));
        float npr = fmaf(pr[i], Pr, -pi[i] * Pi);
        float npi = fmaf(pr[i], Pi,  pi[i] * Pr);
        Hr = nhr; Hi = nhi; Pr = npr; Pi = npi;
    }
    agg_s[cl][g] = make_float4(Pr, Pi, Hr, Hi);
    __syncthreads();

    // exclusive cross-group prefix (g uniform across each 32-lane slice)
    float hr = 0.f, hi = 0.f;
    for (int j = 0; j < g; ++j) {
        float4 a = agg_s[cl][j];
        float nr = fmaf(a.x, hr, fmaf(-a.y, hi, a.z));
        float ni = fmaf(a.x, hi, fmaf( a.y, hr, a.w));
        hr = nr; hi = ni;
    }

    const float Cr = C_param[2 * chain];
    const float Ci = C_param[2 * chain + 1];
    #pragma unroll
    for (int i = 0; i < NGRP; ++i) {
        int c = g * NGRP + i;
        W[c * NCH + chain] = make_float2(fmaf(Cr, hr, -Ci * hi),
                                         fmaf(Cr, hi,  Ci * hr));
        float nr = fmaf(pr[i], hr, fmaf(-pi[i], hi, s[i].x));
        float ni = fmaf(pr[i], hi, fmaf( pi[i], hr, s[i].y));
        hr = nr; hi = ni;
    }
}

// ---------------------------------------------------------------------------
// Kernel 4: correction pass. Thread owns one h (coalesced y1T/out) x 8 l's;
// W row read as 8 x float4 (contiguous 128 B); fast path does 1 setup exp:
//   y = y1 + Re( sum_n exp(A_n*T_l) * W_n )
// ---------------------------------------------------------------------------
__global__ __launch_bounds__(256) void k_corr(const float2* __restrict__ y1T,
        const float* __restrict__ A_log, const float* __restrict__ A_im,
        const float2* __restrict__ W, float* __restrict__ out) {
    const int t = threadIdx.x;
    const int c = blockIdx.x;        // chunk
    const int hl = t & 63;
    const int h = blockIdx.y * 64 + hl;
    const int lb = t >> 6;           // 0..3
    const int l0 = c * CLEN + lb * 8;
    const int hn0 = h * N2d;

    float2 yt[8];
    #pragma unroll
    for (int k = 0; k < 8; ++k) yt[k] = y1T[(l0 + k) * Hd + h];

    float2 w[N2d];
    {
        const float4* w4 = reinterpret_cast<const float4*>(&W[c * NCH + hn0]);
        #pragma unroll
        for (int n = 0; n < 8; ++n) {
            float4 v = w4[n];
            w[2 * n]     = make_float2(v.x, v.y);
            w[2 * n + 1] = make_float2(v.z, v.w);
        }
    }

    float alog[N2d], aim[N2d];
    #pragma unroll
    for (int n = 0; n < N2d; ++n) {
        alog[n] = A_log[hn0 + n];
        aim[n] = A_im[hn0 + n];
    }
    float dA = aim[1] - aim[0];
    bool fast = true;
    #pragma unroll
    for (int n = 1; n < N2d; ++n)
        fast = fast && (alog[n] == alog[0]) && (aim[n] - aim[n - 1] == dA);

    if (fast) {
        const float Are0 = -__expf(alog[0]);
        const float Aim0 = aim[0];
        #pragma unroll
        for (int k = 0; k < 8; ++k) {
            float T = yt[k].y;
            float er = __expf(Are0 * T);
            float s0, c0, sd, cd;
            __sincosf(Aim0 * T, &s0, &c0);
            __sincosf(dA * T, &sd, &cd);
            float ar = er * c0, ai = er * s0;
            float corr = 0.f;
            #pragma unroll
            for (int n = 0; n < N2d; ++n) {
                corr = fmaf(ar, w[n].x, fmaf(-ai, w[n].y, corr));
                if (n < N2d - 1) {
                    float tr = fmaf(ar, cd, -ai * sd);
                    ai = fmaf(ai, cd, ar * sd);
                    ar = tr;
                }
            }
            out[(l0 + k) * Hd + h] = yt[k].x + corr;
        }
    } else {
        float are[N2d];
        #pragma unroll
        for (int n = 0; n < N2d; ++n) are[n] = -__expf(alog[n]);
        #pragma unroll
        for (int k = 0; k < 8; ++k) {
            float T = yt[k].y;
            float corr = 0.f;
            #pragma unroll
            for (int n = 0; n < N2d; ++n) {
                float er = __expf(are[n] * T);
                float s, cc;
                __sincosf(aim[n] * T, &s, &cc);
                corr = fmaf(er * cc, w[n].x, fmaf(-er * s, w[n].y, corr));
            }
            out[(l0 + k) * Hd + h] = yt[k].x + corr;
        }
    }
}

extern "C" void kernel_launch(void* const* d_in, const int* in_sizes, int n_in,
                              void* d_out, int out_size, void* d_ws, size_t ws_size,
                              hipStream_t stream) {
    const float* u        = (const float*)d_in[0];
    const float* A_log    = (const float*)d_in[1];
    const float* A_im     = (const float*)d_in[2];
    const float* B_param  = (const float*)d_in[3];
    const float* C_param  = (const float*)d_in[4];
    const float* Dp       = (const float*)d_in[5];
    const float* dt_w     = (const float*)d_in[6];
    const float* dt_b     = (const float*)d_in[7];
    const float* xproj_w  = (const float*)d_in[8];

    // ws layout: du[L*H f2] | Sb[NCHUNK*NCH f2] | W[NCHUNK*NCH f2]
    //          | y1T[L*H f2] | Tc[Hd*NCHUNK f]
    float2* du  = (float2*)d_ws;
    float2* Sb  = du + (size_t)Ld * Hd;
    float2* W   = Sb + (size_t)NCHUNK * NCH;
    float2* y1T = W + (size_t)NCHUNK * NCH;
    float*  Tc  = (float*)(y1T + (size_t)Ld * Hd);
    float*  out = (float*)d_out;

    k_dt<<<Ld / 8, 256, 0, stream>>>(u, xproj_w, dt_w, dt_b, du);
    dim3 g2(NCHUNK, Hd / 64);
    k_chunk<<<g2, 256, 0, stream>>>(du, A_log, A_im, B_param, C_param, Dp,
                                    Sb, Tc, y1T);
    k_comb<<<NCH / 32, 256, 0, stream>>>(Sb, Tc, A_log, A_im, C_param, W);
    k_corr<<<g2, 256, 0, stream>>>(y1T, A_log, A_im, W, out);
}